// Round 3
// baseline (213.714 us; speedup 1.0000x reference)
//
#include <hip/hip_runtime.h>

typedef unsigned short u16;
typedef __attribute__((ext_vector_type(8))) short bf16x8;
typedef __attribute__((ext_vector_type(4))) float f32x4;

constexpr int SEN   = 128;
constexpr int DC    = 128;
constexpr int CIN   = 270;
constexpr int KP    = 384;    // 3 * 128 (110 variable channels padded to 128)
constexpr int PITCH = 136;    // xT row pitch in u16 (272B rows)
constexpr int ROWS  = 130;    // 128 tokens + 2 zero pad rows
constexpr int NOUT  = 984;
constexpr int XTN   = ROWS * PITCH;

__device__ inline u16 f2bf(float f) {
    unsigned u = __float_as_uint(f);
    return (u16)((u + 0x7FFFu + ((u >> 16) & 1u)) >> 16);
}

struct alignas(8) U16x4 { u16 a, b, c, d; };

__device__ inline bf16x8 pack8(float4 a, float4 b) {
    union { bf16x8 v; u16 u[8]; } p;
    p.u[0] = f2bf(a.x); p.u[1] = f2bf(a.y); p.u[2] = f2bf(a.z); p.u[3] = f2bf(a.w);
    p.u[4] = f2bf(b.x); p.u[5] = f2bf(b.y); p.u[6] = f2bf(b.z); p.u[7] = f2bf(b.w);
    return p.v;
}

// ---------------------------------------------------------------------------
// prep_all: Av (variable-channel weights bf16, K = k*128 + c) + const-channel
// tables SE[k][event][dc], SR[k][slot][role][dc].
// blocks [0,192): Av  [192,252): SE  [252,732): SR
// ---------------------------------------------------------------------------
__global__ void prep_all(const float* __restrict__ w, const float* __restrict__ ee,
                         const float* __restrict__ re,
                         u16* __restrict__ Av, float* __restrict__ SE,
                         float* __restrict__ SR) {
    const int b = blockIdx.x, tid = threadIdx.x;
    if (b < 192) {
        int i = b * 256 + tid;
        int dc = i / KP, K = i - dc * KP;
        int k = K >> 7, c = K & 127;
        float v = (c < 110) ? w[(dc * CIN + c) * 3 + k] : 0.0f;
        Av[i] = f2bf(v);
    } else if (b < 252) {
        int i = (b - 192) * 256 + tid;
        int dc = i & 127, rest = i >> 7;
        int e = rest % 40, k = rest / 40;
        float a = 0.0f;
        for (int j = 0; j < 32; j++)
            a += w[(dc * CIN + 110 + j) * 3 + k] * ee[e * 32 + j];
        SE[(k * 40 + e) * 128 + dc] = a;
    } else {
        int i = (b - 252) * 256 + tid;
        int dc = i & 127, rest = i >> 7;
        int r = rest % 40, rest2 = rest / 40;
        int j = rest2 & 7, k = rest2 >> 3;
        float a = 0.0f;
        for (int d = 0; d < 16; d++)
            a += w[(dc * CIN + 142 + j * 16 + d) * 3 + k] * re[r * 16 + d];
        SR[((k * 8 + j) * 40 + r) * 128 + dc] = a;
    }
}

// ---------------------------------------------------------------------------
// Persistent pipelined kernel: 256 blocks x 512 threads (2 groups x 4 waves).
// Group g of block b owns samples [b*16 + g*8, b*16 + g*8 + 8).
// Pipeline: issue(next) -> GEMM(cur) -> pool/store(cur) -> bar -> commit(next) -> bar
// ---------------------------------------------------------------------------
__global__ __launch_bounds__(512, 2)
void conv_pool(const int* __restrict__ inp, const int* __restrict__ pos1,
               const int* __restrict__ pos2, const int* __restrict__ loc,
               const int* __restrict__ lmark, const int* __restrict__ subtype,
               const int* __restrict__ argRole,
               const float* __restrict__ maskL, const float* __restrict__ maskM,
               const float* __restrict__ maskR,
               const float* __restrict__ we, const float* __restrict__ pe,
               const float* __restrict__ cb,
               const u16* __restrict__ Av, const float* __restrict__ SE,
               const float* __restrict__ SR, float* __restrict__ out)
{
    __shared__ __align__(16) u16 xT[2][XTN];   // 70,720 B
    __shared__ float msk[2][3 * SEN];          //  3,072 B
    __shared__ float sc[2][3 * DC];            //  3,072 B

    const int tid  = threadIdx.x;
    const int grp  = tid >> 8;
    const int j    = tid & 255;
    const int t    = j & 127;
    const int h    = j >> 7;          // wave-uniform half selector
    const int lane = tid & 63;
    const int wv   = (tid >> 6) & 3;  // wave within group: dc slice [wv*32, wv*32+32)
    const int cl   = lane & 15;
    const int rg   = lane >> 4;

    u16*   xTg  = xT[grp];
    float* mskg = msk[grp];
    float* scg  = sc[grp];

    // zero both xT buffers (pad rows 0/129 and cols 110..135 stay zero forever)
    {
        int4 z = {0, 0, 0, 0};
        int4* p = (int4*)xT;
        for (int i = tid; i < 2 * XTN * 2 / 16; i += 512) p[i] = z;
    }

    // A slice into registers, loaded ONCE for the whole persistent block
    bf16x8 A[12][2];
#pragma unroll
    for (int ks = 0; ks < 12; ++ks)
#pragma unroll
        for (int mf = 0; mf < 2; ++mf)
            A[ks][mf] = *(const bf16x8*)(Av + (size_t)(wv * 32 + mf * 16 + cl) * KP
                                         + ks * 32 + rg * 8);

    const int sbase = blockIdx.x * 16 + grp * 8;

    // staged registers
    float4 wf[13];
    float  pp[10];
    float  mk3[3];
    int    sub;
    int4   ar0, ar1;

    auto issue = [&](int s) {
        const int idx = inp[(size_t)s * SEN + t];
        if (h == 0) {
            const float4* src = (const float4*)(we + (size_t)idx * 100);
#pragma unroll
            for (int i = 0; i < 12; ++i) wf[i] = src[i];
            mk3[0] = maskL[(size_t)s * SEN + t];
            mk3[1] = maskM[(size_t)s * SEN + t];
            mk3[2] = maskR[(size_t)s * SEN + t];
            sub = subtype[s];
            const int4* arp = (const int4*)(argRole + (size_t)s * 8);
            ar0 = arp[0]; ar1 = arp[1];
        } else {
            const float4* src = (const float4*)(we + (size_t)idx * 100 + 48);
#pragma unroll
            for (int i = 0; i < 13; ++i) wf[i] = src[i];
            const int p1 = pos1[(size_t)s * SEN + t];
            const int p2 = pos2[(size_t)s * SEN + t];
#pragma unroll
            for (int i = 0; i < 5; ++i) {
                pp[i]     = pe[p1 * 5 + i];
                pp[5 + i] = pe[p2 * 5 + i];
            }
        }
    };

    auto commit = [&](int s) {
        u16* row = xTg + (t + 1) * PITCH;
        if (h == 0) {
#pragma unroll
            for (int i = 0; i < 6; ++i)
                *(bf16x8*)(row + 8 * i) = pack8(wf[2 * i], wf[2 * i + 1]);
            mskg[t]           = mk3[0];
            mskg[SEN + t]     = mk3[1];
            mskg[2 * SEN + t] = mk3[2];
            // const-channel sums, dc = t
            const int arr[8] = {ar0.x, ar0.y, ar0.z, ar0.w, ar1.x, ar1.y, ar1.z, ar1.w};
            float skv[3];
#pragma unroll
            for (int k = 0; k < 3; ++k) {
                float a = SE[(k * 40 + sub) * DC + t];
#pragma unroll
                for (int jj = 0; jj < 8; ++jj)
                    a += SR[((k * 8 + jj) * 40 + arr[jj]) * DC + t];
                skv[k] = a;
            }
            scg[t]          = skv[0] + skv[1] + skv[2] + cb[t];
            scg[DC + t]     = skv[0];
            scg[2 * DC + t] = skv[2];
        } else {
#pragma unroll
            for (int i = 0; i < 6; ++i)
                *(bf16x8*)(row + 48 + 8 * i) = pack8(wf[2 * i], wf[2 * i + 1]);
            {
                U16x4 w4 = { f2bf(wf[12].x), f2bf(wf[12].y),
                             f2bf(wf[12].z), f2bf(wf[12].w) };
                *(U16x4*)(row + 96) = w4;
            }
#pragma unroll
            for (int i = 0; i < 5; ++i) {
                row[100 + i] = f2bf(pp[i]);
                row[105 + i] = f2bf(pp[5 + i]);
            }
            if (t < 100) {   // loc path for this sample
                const int d = t;
                const int* L = loc + (size_t)s * 16;
                float* o = out + (size_t)s * NOUT + 384;
#pragma unroll
                for (int i = 0; i < 4; ++i)
                    o[i * 100 + d] = tanhf(we[(size_t)L[i] * 100 + d]);
                const int mk = lmark[s];
                float acc = 0.f;
                for (int jj = 0; jj < mk; ++jj)
                    acc += we[(size_t)L[4 + jj] * 100 + d];
                o[4 * 100 + d] = tanhf(acc / (float)mk);
                o[5 * 100 + d] = tanhf(we[(size_t)L[4 + mk] * 100 + d]);
            }
        }
    };

    // prologue: stage sample 0 of this group
    issue(sbase);
    commit(sbase);
    __syncthreads();

    for (int it = 0; it < 8; ++it) {
        const int s = sbase + it;
        if (it < 7) issue(s + 1);   // global loads only; latency hides under GEMM

        float pm[3][2][4];
#pragma unroll
        for (int m = 0; m < 3; ++m)
#pragma unroll
            for (int mf = 0; mf < 2; ++mf)
#pragma unroll
                for (int r = 0; r < 4; ++r) pm[m][mf][r] = -1e30f;

#pragma unroll
        for (int half = 0; half < 2; ++half) {
            f32x4 acc[2][4];
#pragma unroll
            for (int mf = 0; mf < 2; ++mf)
#pragma unroll
                for (int nf = 0; nf < 4; ++nf)
                    acc[mf][nf] = (f32x4){0.f, 0.f, 0.f, 0.f};

#pragma unroll
            for (int ks = 0; ks < 12; ++ks) {
                const int krow = ks >> 2;
                const int coff = (ks & 3) * 32 + rg * 8;
                bf16x8 b4[4];
#pragma unroll
                for (int nf = 0; nf < 4; ++nf)
                    b4[nf] = *(const bf16x8*)(xTg
                              + (half * 64 + nf * 16 + cl + krow) * PITCH + coff);
#pragma unroll
                for (int mf = 0; mf < 2; ++mf)
#pragma unroll
                    for (int nf = 0; nf < 4; ++nf)
                        acc[mf][nf] = __builtin_amdgcn_mfma_f32_16x16x32_bf16(
                            A[ks][mf], b4[nf], acc[mf][nf], 0, 0, 0);
            }

            // fold this half into the running masked maxes
            float sall[2][4];
#pragma unroll
            for (int mf = 0; mf < 2; ++mf)
#pragma unroll
                for (int r = 0; r < 4; ++r)
                    sall[mf][r] = scg[wv * 32 + mf * 16 + rg * 4 + r];

#pragma unroll
            for (int nf = 0; nf < 4; ++nf) {
                const int tt = half * 64 + nf * 16 + cl;
                const float m0v = mskg[tt];
                const float m1v = mskg[SEN + tt];
                const float m2v = mskg[2 * SEN + tt];
#pragma unroll
                for (int mf = 0; mf < 2; ++mf)
#pragma unroll
                    for (int r = 0; r < 4; ++r) {
                        const int dc = wv * 32 + mf * 16 + rg * 4 + r;
                        float v = acc[mf][nf][r] + sall[mf][r];
                        if (half == 0 && nf == 0) {           // t == 0 edge
                            float s0 = scg[DC + dc];
                            v -= (cl == 0) ? s0 : 0.f;
                        }
                        if (half == 1 && nf == 3) {           // t == 127 edge
                            float s2 = scg[2 * DC + dc];
                            v -= (cl == 15) ? s2 : 0.f;
                        }
                        pm[0][mf][r] = fmaxf(pm[0][mf][r], __builtin_fmaf(v, m0v, 1.f));
                        pm[1][mf][r] = fmaxf(pm[1][mf][r], __builtin_fmaf(v, m1v, 1.f));
                        pm[2][mf][r] = fmaxf(pm[2][mf][r], __builtin_fmaf(v, m2v, 1.f));
                    }
            }
        }

        // butterfly max over the 16 cl lanes, then 3 lanes store
#pragma unroll
        for (int m = 0; m < 3; ++m)
#pragma unroll
            for (int mf = 0; mf < 2; ++mf)
#pragma unroll
                for (int r = 0; r < 4; ++r) {
#pragma unroll
                    for (int d = 1; d < 16; d <<= 1)
                        pm[m][mf][r] = fmaxf(pm[m][mf][r], __shfl_xor(pm[m][mf][r], d));
                }
        if (cl < 3) {
            float* o = out + (size_t)s * NOUT;
#pragma unroll
            for (int mf = 0; mf < 2; ++mf)
#pragma unroll
                for (int r = 0; r < 4; ++r) {
                    const int dc = wv * 32 + mf * 16 + rg * 4 + r;
                    float vL = pm[0][mf][r], vM = pm[1][mf][r], vR = pm[2][mf][r];
                    float sel = (cl == 0) ? vL : ((cl == 1) ? vM : vR);
                    o[cl * DC + dc] = tanhf(sel - 1.f);
                }
        }

        __syncthreads();                 // all reads of xTg/mskg/scg done
        if (it < 7) commit(s + 1);       // overwrite with next sample
        __syncthreads();
    }
}

// ---------------------------------------------------------------------------
extern "C" void kernel_launch(void* const* d_in, const int* in_sizes, int n_in,
                              void* d_out, int out_size, void* d_ws, size_t ws_size,
                              hipStream_t stream) {
    const int*   inp     = (const int*)d_in[0];
    const int*   pos1    = (const int*)d_in[1];
    const int*   pos2    = (const int*)d_in[2];
    const int*   loc     = (const int*)d_in[3];
    const int*   lmark   = (const int*)d_in[4];
    const int*   subtype = (const int*)d_in[5];
    const int*   argRole = (const int*)d_in[6];
    const float* maskL   = (const float*)d_in[7];
    const float* maskM   = (const float*)d_in[8];
    const float* maskR   = (const float*)d_in[9];
    const float* we      = (const float*)d_in[10];
    const float* pe      = (const float*)d_in[11];
    const float* cw      = (const float*)d_in[14];
    const float* cb      = (const float*)d_in[15];
    float* out = (float*)d_out;

    char* ws = (char*)d_ws;
    u16*   Av = (u16*)ws;                        // 98,304 B
    float* SE = (float*)(ws + 98304);            // 61,440 B
    float* SR = (float*)(ws + 98304 + 61440);    // 491,520 B

    hipLaunchKernelGGL(prep_all, dim3(732), dim3(256), 0, stream,
                       cw, (const float*)d_in[12], (const float*)d_in[13],
                       Av, SE, SR);
    hipLaunchKernelGGL(conv_pool, dim3(256), dim3(512), 0, stream,
                       inp, pos1, pos2, loc, lmark, subtype, argRole,
                       maskL, maskM, maskR, we, pe, cb,
                       Av, SE, SR, out);
}

// Round 4
// 176.170 us; speedup vs baseline: 1.2131x; 1.2131x over previous
//
#include <hip/hip_runtime.h>
#include <hip/hip_bf16.h>

typedef unsigned short u16;
typedef __attribute__((ext_vector_type(8))) short bf16x8;
typedef __attribute__((ext_vector_type(4))) float f32x4;

constexpr int SEN  = 128;
constexpr int DCN  = 128;
constexpr int CIN  = 270;
constexpr int KP   = 384;          // 3 * 128 (110 var channels padded to 128)
constexpr int ROWS = 130;          // 128 tokens + 2 zero pad rows
constexpr int XTW  = 128;          // u16 per row (256 B, 16 slots of 16 B)
constexpr int XTN  = ROWS * XTW;   // 16640 u16 = 33280 B
constexpr int NOUT = 984;

__device__ inline float ftanh(float x) {
    float e = __expf(2.0f * x);
    return 1.0f - 2.0f * __builtin_amdgcn_rcpf(e + 1.0f);
}

__device__ inline unsigned pk2(float x, float y) {
    union { __hip_bfloat162 h; unsigned u; } v;
    v.h = __float22bfloat162_rn(float2{x, y});
    return v.u;
}
__device__ inline bf16x8 pack8(float4 a, float4 b) {
    union { bf16x8 v; unsigned u[4]; } p;
    p.u[0] = pk2(a.x, a.y); p.u[1] = pk2(a.z, a.w);
    p.u[2] = pk2(b.x, b.y); p.u[3] = pk2(b.z, b.w);
    return p.v;
}

// ---------------------------------------------------------------------------
// prep_all: Av (bf16 weights, K = k*128+c), SE3[(e*128+dc)*3+k],
// SR3[((j*40+r)*128+dc)*3+k], plus the independent loc path.
// blocks [0,192): Av  [192,252): SE3  [252,732): SR3  [732,2780): loc
// ---------------------------------------------------------------------------
__global__ void prep_all(const float* __restrict__ w, const float* __restrict__ ee,
                         const float* __restrict__ re, const int* __restrict__ loc,
                         const int* __restrict__ lmark, const float* __restrict__ we,
                         u16* __restrict__ Av, float* __restrict__ SE3,
                         float* __restrict__ SR3, float* __restrict__ out) {
    const int b = blockIdx.x, tid = threadIdx.x;
    if (b < 192) {
        int i = b * 256 + tid;
        int dc = i / KP, K = i - dc * KP;
        int k = K >> 7, c = K & 127;
        float v = (c < 110) ? w[(dc * CIN + c) * 3 + k] : 0.0f;
        union { __hip_bfloat16 h; u16 u; } cv;
        cv.h = __float2bfloat16(v);
        Av[i] = cv.u;
    } else if (b < 252) {
        int i = (b - 192) * 256 + tid;       // < 15360
        int k = i % 3, rest = i / 3;
        int dc = rest & 127, e = rest >> 7;  // e < 40
        float a = 0.f;
        for (int j = 0; j < 32; ++j)
            a += w[(dc * CIN + 110 + j) * 3 + k] * ee[e * 32 + j];
        SE3[i] = a;
    } else if (b < 732) {
        int i = (b - 252) * 256 + tid;       // < 122880
        int k = i % 3, rest = i / 3;
        int dc = rest & 127, rr = rest >> 7; // rr < 320
        int r = rr % 40, j = rr / 40;
        float a = 0.f;
        for (int d = 0; d < 16; ++d)
            a += w[(dc * CIN + 142 + j * 16 + d) * 3 + k] * re[r * 16 + d];
        SR3[i] = a;
    } else {
        int li = b - 732;                    // 0..2047, two samples per block
        int s = li * 2 + (tid >> 7);
        int d = tid & 127;
        if (d < 100) {
            const int* L = loc + (size_t)s * 16;
            float* o = out + (size_t)s * NOUT + 384;
#pragma unroll
            for (int i = 0; i < 4; ++i)
                o[i * 100 + d] = ftanh(we[(size_t)L[i] * 100 + d]);
            int mk = lmark[s];
            float acc = 0.f;
            for (int j = 0; j < mk; ++j)
                acc += we[(size_t)L[4 + j] * 100 + d];
            o[4 * 100 + d] = ftanh(acc / (float)mk);
            o[5 * 100 + d] = ftanh(we[(size_t)L[4 + mk] * 100 + d]);
        }
    }
}

// ---------------------------------------------------------------------------
// Main: 512 blocks x 256 thr (4 waves), persistent 8 samples/block,
// double-buffered swizzled LDS, A register-resident, 1 barrier/sample.
// ---------------------------------------------------------------------------
#define GEMM_HALF(XB, KS0)                                                         \
    {                                                                              \
        const char* xbc = (const char*)(XB);                                       \
        _Pragma("unroll")                                                          \
        for (int kss = 0; kss < 6; ++kss) {                                        \
            const int ks = (KS0) + kss;                                            \
            const int krow = ks >> 2, kk = ks & 3;                                 \
            const int rb = cl + krow;                                              \
            const char* bas = xbc + rb * 256 + (((kk * 4 + rg) ^ (rb & 7)) << 4);  \
            bf16x8 b4[4];                                                          \
            _Pragma("unroll")                                                      \
            for (int nf = 0; nf < 4; ++nf)                                         \
                b4[nf] = *(const bf16x8*)(bas + nf * 4096);                        \
            _Pragma("unroll")                                                      \
            for (int mf = 0; mf < 2; ++mf)                                         \
                _Pragma("unroll")                                                  \
                for (int nf = 0; nf < 4; ++nf)                                     \
                    acc[mf][nf] = __builtin_amdgcn_mfma_f32_16x16x32_bf16(         \
                        A[ks][mf], b4[nf], acc[mf][nf], 0, 0, 0);                  \
            _Pragma("unroll")                                                      \
            for (int nf = 0; nf < 4; ++nf)                                         \
                b4[nf] = *(const bf16x8*)(bas + (nf + 4) * 4096);                  \
            _Pragma("unroll")                                                      \
            for (int mf = 0; mf < 2; ++mf)                                         \
                _Pragma("unroll")                                                  \
                for (int nf = 0; nf < 4; ++nf)                                     \
                    acc[mf][nf + 4] = __builtin_amdgcn_mfma_f32_16x16x32_bf16(     \
                        A[ks][mf], b4[nf], acc[mf][nf + 4], 0, 0, 0);              \
        }                                                                          \
    }

__global__ __attribute__((amdgpu_waves_per_eu(2, 2))) __launch_bounds__(256)
void conv_pool(const int* __restrict__ inp, const int* __restrict__ pos1,
               const int* __restrict__ pos2, const int* __restrict__ subtype,
               const int* __restrict__ argRole,
               const float* __restrict__ maskL, const float* __restrict__ maskM,
               const float* __restrict__ maskR,
               const float* __restrict__ we, const float* __restrict__ pe,
               const float* __restrict__ cb,
               const u16* __restrict__ Av, const float* __restrict__ SE3,
               const float* __restrict__ SR3, float* __restrict__ out)
{
    __shared__ __align__(16) u16 xT[2][XTN];   // 66,560 B
    __shared__ float msk[2][3 * SEN];          //  3,072 B
    __shared__ float sc[2][3 * DCN];           //  3,072 B

    const int tid  = threadIdx.x;
    const int t    = tid & 127;
    const int h    = tid >> 7;        // wave-uniform role (waves 0,1 vs 2,3)
    const int lane = tid & 63;
    const int wv   = tid >> 6;        // dc slice [wv*32, wv*32+32)
    const int cl   = lane & 15;
    const int rg   = lane >> 4;

    // A register-resident for the whole persistent block (96 VGPRs)
    bf16x8 A[12][2];
#pragma unroll
    for (int ks = 0; ks < 12; ++ks)
#pragma unroll
        for (int mf = 0; mf < 2; ++mf)
            A[ks][mf] = *(const bf16x8*)(Av + (wv * 32 + mf * 16 + cl) * KP
                                         + ks * 32 + rg * 8);

    const int sbase = blockIdx.x * 8;

    // staged state (constant-indexed only -> stays in VGPRs)
    int   idx = 0, sub = 0;
    int4  ar0 = {0, 0, 0, 0}, ar1 = {0, 0, 0, 0};
    float stg[44];

    auto stage0_issue = [&](int s) {
        idx = inp[s * SEN + t];
        const float4* wp = (const float4*)(we + (size_t)idx * 100);
        if (h == 0) {
#pragma unroll
            for (int i = 0; i < 8; ++i) {
                float4 v = wp[i];
                stg[4*i] = v.x; stg[4*i+1] = v.y; stg[4*i+2] = v.z; stg[4*i+3] = v.w;
            }
            sub = subtype[s];
            const int4* ap = (const int4*)(argRole + s * 8);
            ar0 = ap[0]; ar1 = ap[1];
        } else {
#pragma unroll
            for (int i = 0; i < 8; ++i) {
                float4 v = wp[8 + i];
                stg[4*i] = v.x; stg[4*i+1] = v.y; stg[4*i+2] = v.z; stg[4*i+3] = v.w;
            }
            stg[32] = maskL[s * SEN + t];
            stg[33] = maskM[s * SEN + t];
            stg[34] = maskR[s * SEN + t];
        }
    };

    auto stage0_commit = [&](u16* xb, float* mb) {
        const int r = t + 1, rx = r & 7;
        char* rp = (char*)xb + r * 256;
        if (h == 0) {
#pragma unroll
            for (int i = 0; i < 4; ++i)
                *(bf16x8*)(rp + ((i ^ rx) << 4)) =
                    pack8(float4{stg[8*i], stg[8*i+1], stg[8*i+2], stg[8*i+3]},
                          float4{stg[8*i+4], stg[8*i+5], stg[8*i+6], stg[8*i+7]});
            bf16x8 z = {0, 0, 0, 0, 0, 0, 0, 0};
            if (t < 16)      *(bf16x8*)((char*)xb + (t << 4)) = z;              // row 0
            else if (t < 32) *(bf16x8*)((char*)xb + 129 * 256 + ((t - 16) << 4)) = z; // row 129
        } else {
#pragma unroll
            for (int i = 0; i < 4; ++i)
                *(bf16x8*)(rp + (((4 + i) ^ rx) << 4)) =
                    pack8(float4{stg[8*i], stg[8*i+1], stg[8*i+2], stg[8*i+3]},
                          float4{stg[8*i+4], stg[8*i+5], stg[8*i+6], stg[8*i+7]});
            mb[t]       = stg[32];
            mb[128 + t] = stg[33];
            mb[256 + t] = stg[34];
        }
    };

    auto stage1_issue = [&](int s) {
        const float* wr = we + (size_t)idx * 100;
        if (h == 0) {
            float4 v = *(const float4*)(wr + 96);            // word cols 96..100
            stg[0] = v.x; stg[1] = v.y; stg[2] = v.z; stg[3] = v.w;
            int p1i = pos1[s * SEN + t], p2i = pos2[s * SEN + t];
#pragma unroll
            for (int i = 0; i < 5; ++i) {
                stg[4 + i] = pe[p1i * 5 + i];
                stg[9 + i] = pe[p2i * 5 + i];
            }
            int arr[8] = {ar0.x, ar0.y, ar0.z, ar0.w, ar1.x, ar1.y, ar1.z, ar1.w};
#pragma unroll
            for (int k = 0; k < 3; ++k)
                stg[14 + k] = SE3[(sub * 128 + t) * 3 + k];
#pragma unroll
            for (int j = 0; j < 8; ++j)
#pragma unroll
                for (int k = 0; k < 3; ++k)
                    stg[17 + j * 3 + k] = SR3[((j * 40 + arr[j]) * 128 + t) * 3 + k];
            stg[41] = cb[t];
        } else {
            const float4* wp = (const float4*)wr;
#pragma unroll
            for (int i = 0; i < 8; ++i) {
                float4 v = wp[16 + i];                        // word cols 64..96
                stg[4*i] = v.x; stg[4*i+1] = v.y; stg[4*i+2] = v.z; stg[4*i+3] = v.w;
            }
        }
    };

    auto stage1_commit = [&](u16* xb, float* scb) {
        const int r = t + 1, rx = r & 7;
        char* rp = (char*)xb + r * 256;
        if (h == 0) {
            // slot 12: word 96..100 + p1[0..4)   slot 13: p1[4], p2[0..5), 0, 0
            *(bf16x8*)(rp + ((12 ^ rx) << 4)) =
                pack8(float4{stg[0], stg[1], stg[2], stg[3]},
                      float4{stg[4], stg[5], stg[6], stg[7]});
            *(bf16x8*)(rp + ((13 ^ rx) << 4)) =
                pack8(float4{stg[8], stg[9], stg[10], stg[11]},
                      float4{stg[12], stg[13], 0.f, 0.f});
            bf16x8 z = {0, 0, 0, 0, 0, 0, 0, 0};
            *(bf16x8*)(rp + ((14 ^ rx) << 4)) = z;
            *(bf16x8*)(rp + ((15 ^ rx) << 4)) = z;
            float skv[3];
#pragma unroll
            for (int k = 0; k < 3; ++k) {
                float a = stg[14 + k];
#pragma unroll
                for (int j = 0; j < 8; ++j) a += stg[17 + j * 3 + k];
                skv[k] = a;
            }
            scb[t]       = skv[0] + skv[1] + skv[2] + stg[41];
            scb[128 + t] = skv[0];
            scb[256 + t] = skv[2];
        } else {
#pragma unroll
            for (int i = 0; i < 4; ++i)
                *(bf16x8*)(rp + (((8 + i) ^ rx) << 4)) =
                    pack8(float4{stg[8*i], stg[8*i+1], stg[8*i+2], stg[8*i+3]},
                          float4{stg[8*i+4], stg[8*i+5], stg[8*i+6], stg[8*i+7]});
        }
    };

    // prologue: stage sample 0 into buffer 0
    stage0_issue(sbase);
    stage0_commit(xT[0], msk[0]);
    stage1_issue(sbase);
    stage1_commit(xT[0], sc[0]);
    __syncthreads();

    for (int it = 0; it < 8; ++it) {
        const int s = sbase + it;
        const int cur = it & 1;
        u16* xc = xT[cur];
        u16* xn = xT[cur ^ 1];

        f32x4 acc[2][8];
#pragma unroll
        for (int mf = 0; mf < 2; ++mf)
#pragma unroll
            for (int nf = 0; nf < 8; ++nf)
                acc[mf][nf] = (f32x4){0.f, 0.f, 0.f, 0.f};

        if (it < 7) stage0_issue(s + 1);
        GEMM_HALF(xc, 0);
        if (it < 7) { stage0_commit(xn, msk[cur ^ 1]); stage1_issue(s + 1); }
        GEMM_HALF(xc, 6);
        if (it < 7) stage1_commit(xn, sc[cur ^ 1]);

        // ---- epilogue: masked max-pool in registers ----
        const float* mc  = msk[cur];
        const float* scc = sc[cur];
        float sall[2][4];
#pragma unroll
        for (int mf = 0; mf < 2; ++mf)
#pragma unroll
            for (int r = 0; r < 4; ++r)
                sall[mf][r] = scc[wv * 32 + mf * 16 + rg * 4 + r];

        float pm[3][2][4];
#pragma unroll
        for (int m = 0; m < 3; ++m)
#pragma unroll
            for (int mf = 0; mf < 2; ++mf)
#pragma unroll
                for (int r = 0; r < 4; ++r) pm[m][mf][r] = -1e30f;

#pragma unroll
        for (int nf = 0; nf < 8; ++nf) {
            const int tt = nf * 16 + cl;
            const float m0v = mc[tt], m1v = mc[128 + tt], m2v = mc[256 + tt];
#pragma unroll
            for (int mf = 0; mf < 2; ++mf)
#pragma unroll
                for (int r = 0; r < 4; ++r) {
                    const int dc = wv * 32 + mf * 16 + rg * 4 + r;
                    float v = acc[mf][nf][r] + sall[mf][r];
                    if (nf == 0) v -= (cl == 0)  ? scc[128 + dc] : 0.f;  // t == 0
                    if (nf == 7) v -= (cl == 15) ? scc[256 + dc] : 0.f;  // t == 127
                    pm[0][mf][r] = fmaxf(pm[0][mf][r], __builtin_fmaf(v, m0v, 1.f));
                    pm[1][mf][r] = fmaxf(pm[1][mf][r], __builtin_fmaf(v, m1v, 1.f));
                    pm[2][mf][r] = fmaxf(pm[2][mf][r], __builtin_fmaf(v, m2v, 1.f));
                }
        }
#pragma unroll
        for (int m = 0; m < 3; ++m)
#pragma unroll
            for (int mf = 0; mf < 2; ++mf)
#pragma unroll
                for (int r = 0; r < 4; ++r)
#pragma unroll
                    for (int d = 1; d < 16; d <<= 1)
                        pm[m][mf][r] = fmaxf(pm[m][mf][r], __shfl_xor(pm[m][mf][r], d));
        if (cl < 3) {
            float* o = out + (size_t)s * NOUT + cl * 128;
#pragma unroll
            for (int mf = 0; mf < 2; ++mf)
#pragma unroll
                for (int r = 0; r < 4; ++r) {
                    const int dc = wv * 32 + mf * 16 + rg * 4 + r;
                    float v = (cl == 0) ? pm[0][mf][r]
                             : (cl == 1) ? pm[1][mf][r] : pm[2][mf][r];
                    o[dc] = ftanh(v - 1.f);
                }
        }
        __syncthreads();
    }
}

// ---------------------------------------------------------------------------
extern "C" void kernel_launch(void* const* d_in, const int* in_sizes, int n_in,
                              void* d_out, int out_size, void* d_ws, size_t ws_size,
                              hipStream_t stream) {
    const int*   inp     = (const int*)d_in[0];
    const int*   pos1    = (const int*)d_in[1];
    const int*   pos2    = (const int*)d_in[2];
    const int*   loc     = (const int*)d_in[3];
    const int*   lmark   = (const int*)d_in[4];
    const int*   subtype = (const int*)d_in[5];
    const int*   argRole = (const int*)d_in[6];
    const float* maskL   = (const float*)d_in[7];
    const float* maskM   = (const float*)d_in[8];
    const float* maskR   = (const float*)d_in[9];
    const float* we      = (const float*)d_in[10];
    const float* pe      = (const float*)d_in[11];
    const float* ee      = (const float*)d_in[12];
    const float* re      = (const float*)d_in[13];
    const float* cw      = (const float*)d_in[14];
    const float* cb      = (const float*)d_in[15];
    float* out = (float*)d_out;

    char* ws = (char*)d_ws;
    u16*   Av  = (u16*)ws;                        // 98,304 B
    float* SE3 = (float*)(ws + 98304);            // 61,440 B
    float* SR3 = (float*)(ws + 98304 + 61440);    // 491,520 B

    hipLaunchKernelGGL(prep_all, dim3(2780), dim3(256), 0, stream,
                       cw, ee, re, loc, lmark, we, Av, SE3, SR3, out);
    hipLaunchKernelGGL(conv_pool, dim3(512), dim3(256), 0, stream,
                       inp, pos1, pos2, subtype, argRole, maskL, maskM, maskR,
                       we, pe, cb, Av, SE3, SR3, out);
}